// Round 7
// baseline (60.331 us; speedup 1.0000x reference)
//
#include <hip/hip_runtime.h>

#define BATCH      4096
#define NCLS       32
#define NCLASSES   512
#define EMBD       128
#define NEMB       16384                 // NCLS * NCLASSES
#define NROWS      (BATCH * NCLS)        // 131072
#define TRBLOCKS   ((NEMB / 32) * (EMBD / 32))   // 2048 transpose blocks
#define ABLOCKS    (NROWS / 16)          // 8192 argmax blocks (16 rows each)
#define BBLOCKS    (NROWS / 8)           // 16384 gather blocks

typedef float f4 __attribute__((ext_vector_type(4)));

// ---------------------------------------------------------------------------
// Kernel A: heterogeneous grid.
//   blocks [0, TRBLOCKS)      : transpose emb (EMBD x NEMB) -> embT
//   blocks [TRBLOCKS, ...)    : streaming argmax, 2 row-pairs (4 rows)/wave
// R7: each wave issues 8 up-front float4 loads (2 independent row-pairs) for
// 2x memory-level parallelism; two independent reduce chains give shfl ILP.
// ---------------------------------------------------------------------------
__global__ __launch_bounds__(256) void vq_tr_argmax(
    const float* __restrict__ onehot, const float* __restrict__ emb,
    float* __restrict__ embT, int* __restrict__ idxout) {

    if (blockIdx.x < TRBLOCKS) {
        __shared__ float tile[32][33];
        const int e0 = (blockIdx.x & (NEMB / 32 - 1)) * 32;
        const int d0 = (blockIdx.x / (NEMB / 32)) * 32;
        const int tx = threadIdx.x & 31;
        const int ty = threadIdx.x >> 5;
#pragma unroll
        for (int k = 0; k < 32; k += 8)
            tile[ty + k][tx] = emb[(size_t)(d0 + ty + k) * NEMB + (e0 + tx)];
        __syncthreads();
#pragma unroll
        for (int k = 0; k < 32; k += 8)
            embT[(size_t)(e0 + ty + k) * EMBD + (d0 + tx)] = tile[tx][ty + k];
        return;
    }

    const int ab   = blockIdx.x - TRBLOCKS;       // 0..ABLOCKS-1
    const int wave = threadIdx.x >> 6;
    const int lane = threadIdx.x & 63;
    const int half = lane >> 5;
    const int hl   = lane & 31;
    // wave handles rows r0, r0+1 (pair P), r0+2, r0+3 (pair Q)
    const int r0   = (ab * 4 + wave) * 4;
    const int rP   = r0 + half;
    const int rQ   = r0 + 2 + half;
    const float* rowP = onehot + (size_t)rP * NCLASSES;
    const float* rowQ = onehot + (size_t)rQ * NCLASSES;

    // ---- issue all 8 loads up front (compiler clusters global_loads) ----
    f4 xP[4], xQ[4];
#pragma unroll
    for (int k = 0; k < 4; ++k)
        xP[k] = *reinterpret_cast<const f4*>(rowP + hl * 4 + k * 128);
#pragma unroll
    for (int k = 0; k < 4; ++k)
        xQ[k] = *reinterpret_cast<const f4*>(rowQ + hl * 4 + k * 128);

    // ---- two independent scans ----
    float vP = -INFINITY, vQ = -INFINITY;
    int   iP = 0,        iQ = 0;
#pragma unroll
    for (int k = 0; k < 4; ++k) {
        const int base = hl * 4 + k * 128;
#pragma unroll
        for (int j = 0; j < 4; ++j) {
            if (xP[k][j] > vP) { vP = xP[k][j]; iP = base + j; }
            if (xQ[k][j] > vQ) { vQ = xQ[k][j]; iQ = base + j; }
        }
    }

    // ---- two independent 32-lane butterflies (ILP) ----
#pragma unroll
    for (int off = 16; off > 0; off >>= 1) {
        const float oP = __shfl_xor(vP, off);
        const int   jP = __shfl_xor(iP, off);
        const float oQ = __shfl_xor(vQ, off);
        const int   jQ = __shfl_xor(iQ, off);
        if (oP > vP || (oP == vP && jP < iP)) { vP = oP; iP = jP; }
        if (oQ > vQ || (oQ == vQ && jQ < iQ)) { vQ = oQ; iQ = jQ; }
    }
    if (hl == 0) {
        idxout[rP] = iP;
        idxout[rQ] = iQ;
    }
}

// ---------------------------------------------------------------------------
// Kernel B: gather + write, c-clustered XCD swizzle (unchanged from R6).
// ---------------------------------------------------------------------------
__global__ __launch_bounds__(256) void vq_gather(
    const int* __restrict__ idx, const float* __restrict__ embT,
    float* __restrict__ out) {
    const int xcd  = blockIdx.x & 7;
    const int slot = blockIdx.x >> 3;                 // 0..2047
    const int g    = xcd >> 1;                        // c-group 0..3
    const int w    = g + 4 * ((xcd & 1) * (BBLOCKS / 8) + slot);  // bijective

    const int wave = threadIdx.x >> 6;
    const int lane = threadIdx.x & 63;
    const int half = lane >> 5;
    const int hl   = lane & 31;
    const int r    = (w * 4 + wave) * 2 + half;

    const int c    = r & (NCLS - 1);
    const int flat = idx[r] + c * NCLASSES;   // uniform per half: broadcast load

    const f4 val = reinterpret_cast<const f4*>(embT + (size_t)flat * EMBD)[hl];
    __builtin_nontemporal_store(
        val, reinterpret_cast<f4*>(out + (size_t)r * EMBD) + hl);
}

// ---------------------------------------------------------------------------
// Fallback (ws too small): fused argmax + direct column gather.
// ---------------------------------------------------------------------------
__global__ __launch_bounds__(256) void vq_fused_cols(
    const float* __restrict__ onehot, const float* __restrict__ emb,
    float* __restrict__ out) {
    const int wave = threadIdx.x >> 6;
    const int lane = threadIdx.x & 63;
    const int half = lane >> 5;
    const int hl   = lane & 31;
    const int r    = (blockIdx.x * 4 + wave) * 2 + half;
    const float* row = onehot + (size_t)r * NCLASSES;

    float v  = -INFINITY;
    int   vi = 0;
#pragma unroll
    for (int k = 0; k < 4; ++k) {
        const int base = hl * 4 + k * 128;
        const f4 x = *reinterpret_cast<const f4*>(row + base);
#pragma unroll
        for (int j = 0; j < 4; ++j)
            if (x[j] > v) { v = x[j]; vi = base + j; }
    }
#pragma unroll
    for (int off = 16; off > 0; off >>= 1) {
        const float ov = __shfl_xor(v, off);
        const int   oi = __shfl_xor(vi, off);
        if (ov > v || (ov == v && oi < vi)) { v = ov; vi = oi; }
    }
    const int c    = r & (NCLS - 1);
    const int flat = vi + c * NCLASSES;
    f4 t;
#pragma unroll
    for (int j = 0; j < 4; ++j)
        t[j] = emb[(size_t)(4 * hl + j) * NEMB + flat];
    reinterpret_cast<f4*>(out + (size_t)r * EMBD)[hl] = t;
}

extern "C" void kernel_launch(void* const* d_in, const int* in_sizes, int n_in,
                              void* d_out, int out_size, void* d_ws, size_t ws_size,
                              hipStream_t stream) {
    const float* onehot = (const float*)d_in[0];   // (4096, 32, 512) f32
    const float* emb    = (const float*)d_in[1];   // (128, 16384)   f32
    float* out          = (float*)d_out;           // (4096, 4096)   f32

    const size_t embT_bytes = (size_t)NEMB * EMBD * sizeof(float);  // 8.4 MB
    const size_t idx_bytes  = (size_t)NROWS * sizeof(int);          // 512 KB

    if (ws_size >= embT_bytes + idx_bytes) {
        float* embT = (float*)d_ws;
        int*   idx  = (int*)((char*)d_ws + embT_bytes);

        vq_tr_argmax<<<TRBLOCKS + ABLOCKS, 256, 0, stream>>>(
            onehot, emb, embT, idx);
        vq_gather<<<BBLOCKS, 256, 0, stream>>>(idx, embT, out);
    } else {
        vq_fused_cols<<<NROWS / 8, 256, 0, stream>>>(onehot, emb, out);
    }
}